// Round 11
// baseline (99.034 us; speedup 1.0000x reference)
//
#include <hip/hip_runtime.h>
#include <stdint.h>

typedef __attribute__((ext_vector_type(8))) __bf16 bf16x8;
typedef __attribute__((ext_vector_type(4))) __bf16 bf16x4;
typedef __attribute__((ext_vector_type(4))) float f32x4;

// barrier WITHOUT vmcnt drain: LDS ops must land, global loads stay in flight
#define LGKM_BAR() do { asm volatile("s_waitcnt lgkmcnt(0)" ::: "memory"); \
                        __builtin_amdgcn_s_barrier(); } while (0)

namespace {
constexpr int N_ = 64, C_ = 512, P_ = 900, K_ = 64;
constexpr int PP = 960;                               // padded P for at
constexpr int PB = 256;                               // phase1 p-tile
constexpr int SROW = 266;                             // Xl row stride (odd dwords)
constexpr size_t TOT_X = (size_t)N_ * C_ * P_;        // 117,964,800 floats
constexpr size_t AT_BYTES = (size_t)N_ * K_ * PP * 2;         // bf16 a' [n][k][960]
constexpr size_t ASUM_OFF = AT_BYTES;                         // f32 [n][k]
constexpr size_t WBR_OFF  = ASUM_OFF + (size_t)N_ * K_ * 4;   // bf16 wbr [c/8][k][c%8]
}

__device__ inline uint32_t pk2(float a, float b) {
  __bf16 x = (__bf16)a, y = (__bf16)b;
  uint16_t xb = *reinterpret_cast<uint16_t*>(&x);
  uint16_t yb = *reinterpret_cast<uint16_t*>(&y);
  return ((uint32_t)yb << 16) | xb;
}

// --- prep: wbr[oct][k][j] = bf16(w[k][oct*8+j]) (A-frag-ready layout); zero asum.
__global__ __launch_bounds__(256) void k_prep_w(const float* __restrict__ w,
                                                __bf16* __restrict__ wbr,
                                                float* __restrict__ asum) {
  const int T = blockIdx.x * 256 + threadIdx.x;      // 0..4095
  const int k = T >> 6, oct = T & 63;
  const float4 a = *reinterpret_cast<const float4*>(w + (size_t)k * C_ + oct * 8);
  const float4 b = *reinterpret_cast<const float4*>(w + (size_t)k * C_ + oct * 8 + 4);
  bf16x8 o = { (__bf16)a.x, (__bf16)a.y, (__bf16)a.z, (__bf16)a.w,
               (__bf16)b.x, (__bf16)b.y, (__bf16)b.z, (__bf16)b.w };
  *reinterpret_cast<bf16x8*>(wbr + ((size_t)oct * K_ + k) * 8) = o;
  asum[T] = 0.f;
}

// --- phase 1: STREAMING x-read. Block = (n, 256-p window): reads 1KB runs per
//     c-row, sweeping c sequentially. 512 thr / 8 waves; wave owns 32 p x 64 k.
//     Depth-2 register ring + dbuf LDS + lgkm-only barriers. W staged in LDS.
__global__ __launch_bounds__(512, 2) void k_phase1(const float* __restrict__ x,
                                                   const __bf16* __restrict__ wbr,
                                                   __bf16* __restrict__ at,
                                                   float* __restrict__ asum) {
  __shared__ __bf16 Xl[2][32][SROW];  // [buf][c][p256+pad] (532B rows, odd-dword)
  __shared__ bf16x8 Wl[4096];         // 64 KB: [oct 0..63][k 0..63]
  __shared__ float ssq_l[PB];
  const int n   = blockIdx.y;
  const int p0  = blockIdx.x * PB;
  const int tid = threadIdx.x;
  const int w   = tid >> 6, l = tid & 63;
  const int l15 = l & 15,  lh = l >> 4;

  // staging map: thread covers c-row sc, local p cols [pq, pq+16)
  const int sc = tid >> 4;            // 0..31
  const int pq = (tid & 15) * 16;     // 0..240
  const float* xrow = x + (size_t)n * C_ * P_ + p0 + pq;  // + (s*32+sc)*900 + i*4

  // W stage: issue loads first
  bf16x8 tw[8];
  #pragma unroll
  for (int it = 0; it < 8; ++it)
    tw[it] = *reinterpret_cast<const bf16x8*>(wbr + (size_t)(it * 512 + tid) * 8);

  float4 f[2][4];                     // depth-2 ring of raw float4 quads
  auto LOAD = [&](int s, int slot) {
    #pragma unroll
    for (int i = 0; i < 4; ++i) {
      const int gp = p0 + pq + i * 4;           // global p of this float4
      if (gp <= P_ - 4)
        f[slot][i] = *reinterpret_cast<const float4*>(
            xrow + (size_t)(s * 32 + sc) * P_ + i * 4);
      else
        f[slot][i] = make_float4(0.f, 0.f, 0.f, 0.f);
    }
  };

  float sq[16];
  #pragma unroll
  for (int j = 0; j < 16; ++j) sq[j] = 0.f;

  auto STORE = [&](int slot, int b) {
    #pragma unroll
    for (int i = 0; i < 4; ++i) {
      const float4 v = f[slot][i];
      sq[i*4+0] = fmaf(v.x, v.x, sq[i*4+0]);
      sq[i*4+1] = fmaf(v.y, v.y, sq[i*4+1]);
      sq[i*4+2] = fmaf(v.z, v.z, sq[i*4+2]);
      sq[i*4+3] = fmaf(v.w, v.w, sq[i*4+3]);
      uint32_t* d = reinterpret_cast<uint32_t*>(&Xl[b][sc][pq + i * 4]);
      d[0] = pk2(v.x, v.y);
      d[1] = pk2(v.z, v.w);
    }
  };

  LOAD(0, 0); LOAD(1, 1);
  #pragma unroll
  for (int it = 0; it < 8; ++it) Wl[it * 512 + tid] = tw[it];
  if (tid < PB) ssq_l[tid] = 0.f;
  STORE(0, 0);
  LGKM_BAR();

  f32x4 acc[2][4] = {};               // [t][m]: p = p0+w*32+t*16+l15, k = 16m+lh*4+r
  #pragma unroll
  for (int s = 0; s < 16; ++s) {
    if (s + 2 < 16) LOAD(s + 2, s & 1);
    bf16x8 a[4];
    #pragma unroll
    for (int m = 0; m < 4; ++m)
      a[m] = Wl[(s * 4 + lh) * 64 + 16 * m + l15];
    #pragma unroll
    for (int t = 0; t < 2; ++t) {
      bf16x8 bb;
      #pragma unroll
      for (int j = 0; j < 8; ++j)
        bb[j] = Xl[s & 1][lh * 8 + j][w * 32 + t * 16 + l15];
      #pragma unroll
      for (int m = 0; m < 4; ++m)
        acc[t][m] = __builtin_amdgcn_mfma_f32_16x16x32_bf16(a[m], bb, acc[t][m], 0, 0, 0);
    }
    if (s < 15) { STORE((s + 1) & 1, (s + 1) & 1); LGKM_BAR(); }
  }

  // ssq: per-thread partials -> LDS atomics -> per-p totals
  #pragma unroll
  for (int j = 0; j < 16; ++j) atomicAdd(&ssq_l[pq + j], sq[j]);
  __syncthreads();

  float invn[2], invs[2];
  bool  val[2];
  int   pp[2];
  #pragma unroll
  for (int t = 0; t < 2; ++t) {
    pp[t]   = p0 + w * 32 + t * 16 + l15;
    invn[t] = 1.f / fmaxf(sqrtf(ssq_l[w * 32 + t * 16 + l15]), 1e-12f);
    val[t]  = pp[t] < P_;
  }
  float ps[2] = {0.f, 0.f};
  #pragma unroll
  for (int t = 0; t < 2; ++t)
    #pragma unroll
    for (int m = 0; m < 4; ++m)
      #pragma unroll
      for (int r = 0; r < 4; ++r) {
        acc[t][m][r] = __expf(acc[t][m][r] * invn[t]);  // maxless: |logit| <= ~0.5
        ps[t] += acc[t][m][r];
      }
  #pragma unroll
  for (int t = 0; t < 2; ++t) {
    ps[t] += __shfl_xor(ps[t], 16, 64);
    ps[t] += __shfl_xor(ps[t], 32, 64);
    invs[t] = 1.f / ps[t];
  }

  #pragma unroll
  for (int t = 0; t < 2; ++t) {
    if (pp[t] < PP) {
      const float sc2 = invs[t] * invn[t];
      #pragma unroll
      for (int m = 0; m < 4; ++m)
        #pragma unroll
        for (int r = 0; r < 4; ++r) {
          const int k = 16 * m + lh * 4 + r;
          at[((size_t)n * K_ + k) * PP + pp[t]] =
              val[t] ? (__bf16)(acc[t][m][r] * sc2) : (__bf16)0.f;
        }
    }
  }
  #pragma unroll
  for (int m = 0; m < 4; ++m)
    #pragma unroll
    for (int r = 0; r < 4; ++r) {
      float v = 0.f;
      #pragma unroll
      for (int t = 0; t < 2; ++t)
        v += val[t] ? acc[t][m][r] * invs[t] : 0.f;
      v += __shfl_xor(v, 1, 64); v += __shfl_xor(v, 2, 64);
      v += __shfl_xor(v, 4, 64); v += __shfl_xor(v, 8, 64);
      if (l15 == 0)
        unsafeAtomicAdd(asum + n * K_ + 16 * m + lh * 4 + r, v);
    }
}

// --- phase 2 (unchanged): vlad[k][c] = sum_p a'[k][p]*x[c][p] - asum[k]*cent[k][c]
__global__ __launch_bounds__(256) void k_phase2(const float* __restrict__ x,
                                                const __bf16* __restrict__ at,
                                                const float* __restrict__ asum,
                                                const float* __restrict__ cent,
                                                float* __restrict__ out) {
  __shared__ __bf16 Al[2][64][40];   // [buf][k][p32+pad]
  __shared__ __bf16 Xl[2][64][40];   // [buf][c][p32+pad]
  const int n   = blockIdx.y;
  const int c0  = blockIdx.x * 64;
  const int tid = threadIdx.x;
  const int w   = tid >> 6, l = tid & 63;
  const int l15 = l & 15,  lh = l >> 4;

  const int ak  = tid >> 2, ach = tid & 3;      // A staging: k, p-octet
  const int xc  = tid >> 3, xch = tid & 7;      // X staging (x2): c, p-quad
  const size_t abase  = ((size_t)n * K_ + ak) * PP + ach * 8;
  const size_t xbase0 = ((size_t)n * C_ + c0 + xc) * P_ + xch * 4;
  const size_t xbase1 = ((size_t)n * C_ + c0 + xc + 32) * P_ + xch * 4;

  f32x4 acc[4] = {};                 // frag m: k=16m+lh*4+r, c=c0+16w+l15
  bf16x8 na; float4 v0, v1;

  auto LOAD = [&](int s) {
    na = *reinterpret_cast<const bf16x8*>(at + abase + s * 32);
    size_t o0 = xbase0 + s * 32; if (o0 > TOT_X - 4) o0 = TOT_X - 4;
    size_t o1 = xbase1 + s * 32; if (o1 > TOT_X - 4) o1 = TOT_X - 4;
    v0 = *reinterpret_cast<const float4*>(x + o0);
    v1 = *reinterpret_cast<const float4*>(x + o1);
  };
  auto STORE = [&](int b) {
    *reinterpret_cast<bf16x8*>(&Al[b][ak][ach * 8]) = na;
    bf16x4 p0 = { (__bf16)v0.x, (__bf16)v0.y, (__bf16)v0.z, (__bf16)v0.w };
    bf16x4 p1 = { (__bf16)v1.x, (__bf16)v1.y, (__bf16)v1.z, (__bf16)v1.w };
    *reinterpret_cast<bf16x4*>(&Xl[b][xc][xch * 4])      = p0;
    *reinterpret_cast<bf16x4*>(&Xl[b][xc + 32][xch * 4]) = p1;
  };

  LOAD(0); STORE(0);
  LGKM_BAR();

  #pragma unroll 2
  for (int s = 0; s < 29; ++s) {     // K-dim p: 29 steps of 32 (at pad = 0)
    if (s < 28) LOAD(s + 1);
    bf16x8 b = *reinterpret_cast<const bf16x8*>(&Xl[s & 1][16 * w + l15][lh * 8]);
    #pragma unroll
    for (int m = 0; m < 4; ++m) {
      bf16x8 a = *reinterpret_cast<const bf16x8*>(&Al[s & 1][16 * m + l15][lh * 8]);
      acc[m] = __builtin_amdgcn_mfma_f32_16x16x32_bf16(a, b, acc[m], 0, 0, 0);
    }
    if (s < 28) STORE((s + 1) & 1);
    LGKM_BAR();
  }

  const int c = c0 + 16 * w + l15;
  #pragma unroll
  for (int m = 0; m < 4; ++m) {
    #pragma unroll
    for (int r = 0; r < 4; ++r) {
      const int k = 16 * m + lh * 4 + r;
      out[((size_t)n * K_ + k) * C_ + c] =
          acc[m][r] - asum[n * K_ + k] * cent[(size_t)k * C_ + c];
    }
  }
}

extern "C" void kernel_launch(void* const* d_in, const int* in_sizes, int n_in,
                              void* d_out, int out_size, void* d_ws, size_t ws_size,
                              hipStream_t stream) {
  const float* x    = (const float*)d_in[0];
  const float* w    = (const float*)d_in[1];
  const float* cent = (const float*)d_in[2];
  float* out = (float*)d_out;
  char* wsb  = (char*)d_ws;
  __bf16* at   = (__bf16*)wsb;
  float*  asum = (float*)(wsb + ASUM_OFF);
  __bf16* wbr  = (__bf16*)(wsb + WBR_OFF);

  k_prep_w<<<dim3(16), dim3(256), 0, stream>>>(w, wbr, asum);
  k_phase1<<<dim3(4, 64), dim3(512), 0, stream>>>(x, wbr, at, asum);
  k_phase2<<<dim3(8, 64), dim3(256), 0, stream>>>(x, at, asum, cent, out);
}